// Round 19
// baseline (41.861 us; speedup 1.0000x reference)
//
#include <hip/hip_runtime.h>
#include <hip/hip_bf16.h>
#include <math.h>

// Problem constants: B=4, Q=100, T=20, H=W=128 (HW=16384), C=80
#define B_ 4
#define Q_ 100
#define T_ 20
#define C_ 80
#define HW_ 16384
#define HW4_ (HW_ / 4)

#define S_ 16                     // segments over HW
#define QG_ 4                     // queries per wave group
#define NQG_ (Q_ / QG_)           // 25
#define TW_ 5                     // targets per wave (4 waves = 4 t-strips)
#define GR_ 2048                  // uint4 granules (8 f16 px) per row
#define SGR_ (GR_ / S_)           // 128 granules per row-slice
#define NIT_ (SGR_ / 64)          // 2 iterations per wave
#define RT_ (B_ * Q_ + B_ * T_)   // 480 rows total (o then g)
#define NWG_ (B_ * NQG_ * S_)     // 1600 blocks

// Workspace layout: f16 area [RT_][HW_], then floats: rowsum[480], WL, WI
#define H16_ELEMS ((size_t)RT_ * HW_)          // 7,864,320 f16
#define RS_F (H16_ELEMS / 2)                   // float idx 3,932,160
#define WL_F (RS_F + 512)                      // rowsum padded
#define WI_F (WL_F + (size_t)B_ * Q_ * T_ * S_ * 4)

typedef float f32x4 __attribute__((ext_vector_type(4)));
typedef unsigned u32x2 __attribute__((ext_vector_type(2)));
typedef unsigned u32x4 __attribute__((ext_vector_type(4)));
typedef _Float16 half2_t __attribute__((ext_vector_type(2)));

__device__ __forceinline__ half2_t h2cast(unsigned u) {
    half2_t r; __builtin_memcpy(&r, &u, 4); return r;
}
__device__ __forceinline__ unsigned u32cast(half2_t v) {
    unsigned u; __builtin_memcpy(&u, &v, 4); return u;
}
__device__ __forceinline__ half2_t habs2(half2_t v) {
    return h2cast(u32cast(v) & 0x7FFF7FFFu);
}
__device__ __forceinline__ unsigned pkrtz_u32(float x, float y) {
    const auto a = __builtin_amdgcn_cvt_pkrtz(x, y);   // native __fp16x2
    unsigned u; __builtin_memcpy(&u, &a, 4); return u;
}

// 4-stage reduce: lanes 0..3 hold disjoint 16-lane partials (sum = wave sum).
__device__ __forceinline__ float wred4(float v) {
    v += __shfl_down(v, 32);
    v += __shfl_down(v, 16);
    v += __shfl_down(v, 8);
    v += __shfl_down(v, 4);
    return v;
}

// ---------- Kernel A: f32 -> f16 convert (nt both ways) + exact f32 row sums ----------
__global__ __launch_bounds__(256) void convert_kernel(const float* __restrict__ outm,
                                                      const float* __restrict__ tgtm,
                                                      _Float16* __restrict__ h16,
                                                      float* __restrict__ fws) {
    const int row = blockIdx.x;                // 0..479
    const float* src = (row < B_ * Q_) ? outm + (size_t)row * HW_
                                       : tgtm + (size_t)(row - B_ * Q_) * HW_;
    const f32x4* s4 = (const f32x4*)src;
    u32x2* d2 = (u32x2*)(h16 + (size_t)row * HW_);

    float sum = 0.f;
    for (int k = threadIdx.x; k < HW4_; k += 256) {
        const f32x4 v = __builtin_nontemporal_load(s4 + k);
        sum += (v.x + v.y) + (v.z + v.w);
        u32x2 u;
        u.x = pkrtz_u32(v.x, v.y);
        u.y = pkrtz_u32(v.z, v.w);
        __builtin_nontemporal_store(u, d2 + k);
    }
    sum += __shfl_down(sum, 32); sum += __shfl_down(sum, 16);
    sum += __shfl_down(sum, 8);  sum += __shfl_down(sum, 4);
    sum += __shfl_down(sum, 2);  sum += __shfl_down(sum, 1);
    __shared__ float red[4];
    if ((threadIdx.x & 63) == 0) red[threadIdx.x >> 6] = sum;
    __syncthreads();
    if (threadIdx.x == 0) fws[RS_F + row] = red[0] + red[1] + red[2] + red[3];
}

// ---------- Kernel B: fp16 pair kernel, 4q x 5t per wave, 2-deep o-prefetch ----------
__device__ __forceinline__ void cell(u32x4 o, u32x4 g, float& L, float& I) {
    const half2_t o0 = h2cast(o.x), o1 = h2cast(o.y), o2 = h2cast(o.z), o3 = h2cast(o.w);
    const half2_t q0 = h2cast(g.x), q1 = h2cast(g.y), q2 = h2cast(g.z), q3 = h2cast(g.w);
    I = __builtin_amdgcn_fdot2(o0, q0, I, false);
    I = __builtin_amdgcn_fdot2(o1, q1, I, false);
    I = __builtin_amdgcn_fdot2(o2, q2, I, false);
    I = __builtin_amdgcn_fdot2(o3, q3, I, false);
    const half2_t d0 = habs2(o0 - q0), d1 = habs2(o1 - q1);
    const half2_t d2 = habs2(o2 - q2), d3 = habs2(o3 - q3);
    const half2_t s = (d0 + d1) + (d2 + d3);
    half2_t ones; ones.x = (_Float16)1.f; ones.y = (_Float16)1.f;
    L = __builtin_amdgcn_fdot2(s, ones, L, false);
}

__global__ __launch_bounds__(256) void partial_kernel(const _Float16* __restrict__ h16,
                                                      float* __restrict__ fws) {
    // XCD-batch partition: batch b on XCD pair {2b,2b+1} (1600 blocks, 200/XCD).
    const int r = blockIdx.x & 7;
    const int m = blockIdx.x >> 3;
    const int b = r >> 1;
    const int l = m * 2 + (r & 1);        // [0,400): qg(25) x seg(16)
    const int qg = l >> 4;
    const int seg = l & (S_ - 1);

    const int lane = threadIdx.x & 63;
    const int ts   = threadIdx.x >> 6;    // t-strip
    const int t0   = ts * TW_;

    const u32x4* ob = (const u32x4*)(h16 + (size_t)(b * Q_ + qg * QG_) * HW_) + seg * SGR_ + lane;
    const u32x4* gb = (const u32x4*)(h16 + (size_t)(B_ * Q_ + b * T_) * HW_) + seg * SGR_ + lane;

    float accL[QG_][TW_], accI[QG_][TW_];
#pragma unroll
    for (int qi = 0; qi < QG_; ++qi)
#pragma unroll
        for (int tj = 0; tj < TW_; ++tj) { accL[qi][tj] = 0.f; accI[qi][tj] = 0.f; }

    // Prologue: o chunk 0 into registers.
    u32x4 oc[QG_], on[QG_];
#pragma unroll
    for (int qi = 0; qi < QG_; ++qi) oc[qi] = ob[(size_t)qi * GR_];

#pragma unroll
    for (int it = 0; it < NIT_; ++it) {
        const int ofs = it * 64;
        // g loads for this iter FIRST (compute's wait gate), then o(i+1) prefetch
        // (stays outstanding across the g-wait: vmcnt is issue-ordered).
        u32x4 g[TW_];
#pragma unroll
        for (int tj = 0; tj < TW_; ++tj) g[tj] = gb[(size_t)(t0 + tj) * GR_ + ofs];
        if (it + 1 < NIT_) {
#pragma unroll
            for (int qi = 0; qi < QG_; ++qi) on[qi] = ob[(size_t)qi * GR_ + ofs + 64];
        }
#pragma unroll
        for (int tj = 0; tj < TW_; ++tj) {
#pragma unroll
            for (int qi = 0; qi < QG_; ++qi)
                cell(oc[qi], g[tj], accL[qi][tj], accI[qi][tj]);
        }
        if (it + 1 < NIT_) {
#pragma unroll
            for (int qi = 0; qi < QG_; ++qi) oc[qi] = on[qi];
        }
    }

    // Epilogue: 4-stage reduces; lanes 0..3 write sub-partials.
    float* WL = fws + WL_F;
    float* WI = fws + WI_F;
#pragma unroll
    for (int qi = 0; qi < QG_; ++qi) {
        const int bq = b * Q_ + qg * QG_ + qi;
#pragma unroll
        for (int tj = 0; tj < TW_; ++tj) {
            const float vL = wred4(accL[qi][tj]);
            const float vI = wred4(accI[qi][tj]);
            if (lane < 4) {
                const size_t idx = ((size_t)bq * T_ + t0 + tj) * (S_ * 4) + seg * 4 + lane;
                WL[idx] = vL;
                WI[idx] = vI;
            }
        }
    }
}

// ---------- Kernel C: reduce + softmax/dice epilogue ----------
__global__ __launch_bounds__(64) void finalize_kernel(const float* __restrict__ probs,
                                                      const int*   __restrict__ labels,
                                                      const float* __restrict__ fws,
                                                      float* __restrict__ out) {
    const int bq = blockIdx.x;
    const int b = bq / Q_;

    __shared__ float s_logit[C_];
    for (int c = threadIdx.x; c < C_; c += 64)
        s_logit[c] = probs[(size_t)bq * C_ + c];
    __syncthreads();

    const int t = threadIdx.x;
    if (t < T_) {
        const float4* WL4 = (const float4*)(fws + WL_F) + ((size_t)bq * T_ + t) * S_;
        const float4* WI4 = (const float4*)(fws + WI_F) + ((size_t)bq * T_ + t) * S_;
        float L = 0.f, I = 0.f;
#pragma unroll
        for (int s = 0; s < S_; ++s) {
            const float4 a = WL4[s];
            const float4 v = WI4[s];
            L += (a.x + a.y) + (a.z + a.w);
            I += (v.x + v.y) + (v.z + v.w);
        }
        const float osum = fws[RS_F + bq];
        const float tsum = fws[RS_F + B_ * Q_ + b * T_ + t];

        float mx = -INFINITY;
#pragma unroll
        for (int c = 0; c < C_; ++c) mx = fmaxf(mx, s_logit[c]);
        float sum = 0.f;
#pragma unroll
        for (int c = 0; c < C_; ++c) sum += __expf(s_logit[c] - mx);
        const int lab = labels[(size_t)b * T_ + t];
        const float p = __expf(s_logit[lab] - mx) / sum;

        const float denom = osum + tsum;
        const float dice = 1.f - (2.f * I + 1.f) / (denom + 1.f);

        out[(size_t)bq * T_ + t] = L - p + dice;
    }
}

extern "C" void kernel_launch(void* const* d_in, const int* in_sizes, int n_in,
                              void* d_out, int out_size, void* d_ws, size_t ws_size,
                              hipStream_t stream) {
    const float* out_probs     = (const float*)d_in[0]; // [B,Q,C]
    const float* out_masks     = (const float*)d_in[1]; // [B,Q,H,W]
    const float* target_masks  = (const float*)d_in[2]; // [B,T,H,W]
    const int*   target_labels = (const int*)d_in[3];   // [B,T]
    float* out = (float*)d_out;                         // [B,Q,T]

    _Float16* h16 = (_Float16*)d_ws;                    // 15.7 MB f16 area
    float* fws    = (float*)d_ws;                       // float view (offsets RS_F/WL_F/WI_F)

    convert_kernel<<<RT_, 256, 0, stream>>>(out_masks, target_masks, h16, fws);
    partial_kernel<<<NWG_, 256, 0, stream>>>(h16, fws);
    finalize_kernel<<<B_ * Q_, 64, 0, stream>>>(out_probs, target_labels, fws, out);
}

// Round 20
// 37.563 us; speedup vs baseline: 1.1144x; 1.1144x over previous
//
#include <hip/hip_runtime.h>
#include <hip/hip_bf16.h>
#include <math.h>

// Problem constants: B=4, Q=100, T=20, H=W=128 (HW=16384), C=80
#define B_ 4
#define Q_ 100
#define T_ 20
#define C_ 80
#define HW_ 16384
#define HW4_ (HW_ / 4)

#define S_ 8                      // segments over HW
#define QP_ (Q_ / 2)              // 50 query-pairs
#define SEGF4_ (HW4_ / S_)        // 512 f32x4 per (row,seg) slice
#define SEGG_ (HW_ / 8 / S_)      // 256 fp16-granules (8px/16B) per (row,seg)
#define NIT_ 4                    // 4 iterations/wave (64 lanes x 8 px x 4 = 2048 px)
#define TW_ 5                     // targets per wave (4 waves = 4 t-strips)

// Workspace: fp16 g area [B*T][HW], then floats WL/WI/OS/GS (sub-partials [..][S_][4])
#define G16_ELEMS ((size_t)B_ * T_ * HW_)     // 1,310,720 f16
#define FB_ (G16_ELEMS / 2)                   // float idx 655,360
#define WL_F FB_
#define WI_F (WL_F + (size_t)B_ * Q_ * T_ * S_ * 4)
#define OS_F (WI_F + (size_t)B_ * Q_ * T_ * S_ * 4)
#define GS_F (OS_F + (size_t)B_ * Q_ * S_ * 4)

typedef float f32x4 __attribute__((ext_vector_type(4)));
typedef unsigned u32x2 __attribute__((ext_vector_type(2)));
typedef unsigned u32x4 __attribute__((ext_vector_type(4)));
typedef _Float16 half2_t __attribute__((ext_vector_type(2)));

__device__ __forceinline__ half2_t h2cast(unsigned u) {
    half2_t r; __builtin_memcpy(&r, &u, 4); return r;
}
__device__ __forceinline__ unsigned u32cast(half2_t v) {
    unsigned u; __builtin_memcpy(&u, &v, 4); return u;
}
__device__ __forceinline__ half2_t habs2(half2_t v) {
    return h2cast(u32cast(v) & 0x7FFF7FFFu);
}
__device__ __forceinline__ unsigned pkrtz_u32(float x, float y) {
    const auto a = __builtin_amdgcn_cvt_pkrtz(x, y);   // native __fp16x2
    unsigned u; __builtin_memcpy(&u, &a, 4); return u;
}

// 4-stage reduce: lanes 0..3 hold disjoint 16-lane partials (sum = wave sum).
__device__ __forceinline__ float wred4(float v) {
    v += __shfl_down(v, 32);
    v += __shfl_down(v, 16);
    v += __shfl_down(v, 8);
    v += __shfl_down(v, 4);
    return v;
}

// ---------- Kernel A: g rows f32 -> f16 (pure stream; 320 blocks) ----------
__global__ __launch_bounds__(256) void gconv_kernel(const float* __restrict__ tgtm,
                                                    _Float16* __restrict__ g16) {
    const int row  = blockIdx.x >> 2;          // 0..79
    const int part = blockIdx.x & 3;           // row split 4 ways
    const f32x4* s4 = (const f32x4*)(tgtm + (size_t)row * HW_);
    u32x2* d2 = (u32x2*)(g16 + (size_t)row * HW_);
    const int base = part * (HW4_ / 4);
    for (int k = threadIdx.x; k < HW4_ / 4; k += 256) {
        const f32x4 v = __builtin_nontemporal_load(s4 + base + k);
        u32x2 u;
        u.x = pkrtz_u32(v.x, v.y);
        u.y = pkrtz_u32(v.z, v.w);
        __builtin_nontemporal_store(u, d2 + base + k);
    }
}

// ---------- Kernel B: hybrid partial (o f32 direct, g fp16), 2q x 5t / wave ----------
__device__ __forceinline__ void cell(u32x4 o, u32x4 g, float& L, float& I) {
    const half2_t o0 = h2cast(o.x), o1 = h2cast(o.y), o2 = h2cast(o.z), o3 = h2cast(o.w);
    const half2_t q0 = h2cast(g.x), q1 = h2cast(g.y), q2 = h2cast(g.z), q3 = h2cast(g.w);
    I = __builtin_amdgcn_fdot2(o0, q0, I, false);
    I = __builtin_amdgcn_fdot2(o1, q1, I, false);
    I = __builtin_amdgcn_fdot2(o2, q2, I, false);
    I = __builtin_amdgcn_fdot2(o3, q3, I, false);
    const half2_t d0 = habs2(o0 - q0), d1 = habs2(o1 - q1);
    const half2_t d2 = habs2(o2 - q2), d3 = habs2(o3 - q3);
    const half2_t s = (d0 + d1) + (d2 + d3);
    half2_t ones; ones.x = (_Float16)1.f; ones.y = (_Float16)1.f;
    L = __builtin_amdgcn_fdot2(s, ones, L, false);
}

template <bool WITH_G>
__device__ __forceinline__ void partial_body(const f32x4* __restrict__ o0p,  // q0 +seg
                                             const f32x4* __restrict__ o1p,  // q1 +seg
                                             const u32x4* __restrict__ gb,   // g16 +seg
                                             float* __restrict__ fws,
                                             int qpair, int b, int seg,
                                             int lane, int ts) {
    const int t0 = ts * TW_;

    float accL[2][TW_], accI[2][TW_], os[2], gs[TW_];
#pragma unroll
    for (int qi = 0; qi < 2; ++qi) {
        os[qi] = 0.f;
#pragma unroll
        for (int tj = 0; tj < TW_; ++tj) { accL[qi][tj] = 0.f; accI[qi][tj] = 0.f; }
    }
#pragma unroll
    for (int tj = 0; tj < TW_; ++tj) gs[tj] = 0.f;

#pragma unroll
    for (int it = 0; it < NIT_; ++it) {
        // g first (compute's wait gate), then o (HBM, overlaps)
        u32x4 g[TW_];
#pragma unroll
        for (int tj = 0; tj < TW_; ++tj)
            g[tj] = gb[(size_t)(t0 + tj) * (HW_ / 8) + it * 64 + lane];
        const int fo = it * 128 + 2 * lane;
        const f32x4 a0 = o0p[fo], a1 = o0p[fo + 1];      // q0: px 8l..8l+7
        const f32x4 b0 = o1p[fo], b1 = o1p[fo + 1];      // q1

        if (ts == 0) {   // exact f32 osum, one t-strip only
            os[0] += ((a0.x + a0.y) + (a0.z + a0.w)) + ((a1.x + a1.y) + (a1.z + a1.w));
            os[1] += ((b0.x + b0.y) + (b0.z + b0.w)) + ((b1.x + b1.y) + (b1.z + b1.w));
        }
        if (WITH_G) {
            half2_t ones; ones.x = (_Float16)1.f; ones.y = (_Float16)1.f;
#pragma unroll
            for (int tj = 0; tj < TW_; ++tj) {
                gs[tj] = __builtin_amdgcn_fdot2(h2cast(g[tj].x), ones, gs[tj], false);
                gs[tj] = __builtin_amdgcn_fdot2(h2cast(g[tj].y), ones, gs[tj], false);
                gs[tj] = __builtin_amdgcn_fdot2(h2cast(g[tj].z), ones, gs[tj], false);
                gs[tj] = __builtin_amdgcn_fdot2(h2cast(g[tj].w), ones, gs[tj], false);
            }
        }
        // pack o to fp16 in-register
        u32x4 oq0, oq1;
        oq0.x = pkrtz_u32(a0.x, a0.y); oq0.y = pkrtz_u32(a0.z, a0.w);
        oq0.z = pkrtz_u32(a1.x, a1.y); oq0.w = pkrtz_u32(a1.z, a1.w);
        oq1.x = pkrtz_u32(b0.x, b0.y); oq1.y = pkrtz_u32(b0.z, b0.w);
        oq1.z = pkrtz_u32(b1.x, b1.y); oq1.w = pkrtz_u32(b1.z, b1.w);
#pragma unroll
        for (int tj = 0; tj < TW_; ++tj) {
            cell(oq0, g[tj], accL[0][tj], accI[0][tj]);
            cell(oq1, g[tj], accL[1][tj], accI[1][tj]);
        }
    }

    // Epilogue: 4-stage reduces; lanes 0..3 write sub-partials.
    float* WL = fws + WL_F;
    float* WI = fws + WI_F;
    float* OS = fws + OS_F;
    float* GS = fws + GS_F;
#pragma unroll
    for (int qi = 0; qi < 2; ++qi) {
        const int bq = b * Q_ + qpair * 2 + qi;
#pragma unroll
        for (int tj = 0; tj < TW_; ++tj) {
            const float vL = wred4(accL[qi][tj]);
            const float vI = wred4(accI[qi][tj]);
            if (lane < 4) {
                const size_t idx = ((size_t)bq * T_ + t0 + tj) * (S_ * 4) + seg * 4 + lane;
                WL[idx] = vL;
                WI[idx] = vI;
            }
        }
        if (ts == 0) {
            const float vo = wred4(os[qi]);
            if (lane < 4) OS[(size_t)bq * (S_ * 4) + seg * 4 + lane] = vo;
        }
    }
    if (WITH_G) {
#pragma unroll
        for (int tj = 0; tj < TW_; ++tj) {
            const float vg = wred4(gs[tj]);
            if (lane < 4) GS[(size_t)(b * T_ + t0 + tj) * (S_ * 4) + seg * 4 + lane] = vg;
        }
    }
}

__global__ __launch_bounds__(256) void partial_kernel(const float* __restrict__ outm,
                                                      const _Float16* __restrict__ g16,
                                                      float* __restrict__ fws) {
    // XCD-batch partition: batch b on XCD pair {2b,2b+1}.
    const int r = blockIdx.x & 7;
    const int m = blockIdx.x >> 3;
    const int b = r >> 1;
    const int l = m * 2 + (r & 1);   // [0,400): qp(50) x seg(8)
    const int qp = l >> 3;
    const int seg = l & (S_ - 1);

    const int lane = threadIdx.x & 63;
    const int ts   = threadIdx.x >> 6;   // t-strip = wave id

    const f32x4* o0p = (const f32x4*)(outm + ((size_t)b * Q_ + qp * 2) * HW_) + seg * SEGF4_;
    const f32x4* o1p = o0p + HW4_;
    const u32x4* gb  = (const u32x4*)(g16 + (size_t)b * T_ * HW_) + seg * SEGG_;

    if (qp == 0) partial_body<true>(o0p, o1p, gb, fws, qp, b, seg, lane, ts);
    else         partial_body<false>(o0p, o1p, gb, fws, qp, b, seg, lane, ts);
}

// ---------- Kernel C: reduce + softmax/dice epilogue ----------
__global__ __launch_bounds__(64) void finalize_kernel(const float* __restrict__ probs,
                                                      const int*   __restrict__ labels,
                                                      const float* __restrict__ fws,
                                                      float* __restrict__ out) {
    const int bq = blockIdx.x;
    const int b = bq / Q_;

    __shared__ float s_logit[C_];
    for (int c = threadIdx.x; c < C_; c += 64)
        s_logit[c] = probs[(size_t)bq * C_ + c];
    __syncthreads();

    const int t = threadIdx.x;
    if (t < T_) {
        const float4* WL4 = (const float4*)(fws + WL_F) + ((size_t)bq * T_ + t) * S_;
        const float4* WI4 = (const float4*)(fws + WI_F) + ((size_t)bq * T_ + t) * S_;
        const float4* OS4 = (const float4*)(fws + OS_F) + (size_t)bq * S_;
        const float4* GS4 = (const float4*)(fws + GS_F) + ((size_t)b * T_ + t) * S_;
        float L = 0.f, I = 0.f, osum = 0.f, tsum = 0.f;
#pragma unroll
        for (int s = 0; s < S_; ++s) {
            const float4 a = WL4[s];
            const float4 v = WI4[s];
            const float4 c = OS4[s];
            const float4 d = GS4[s];
            L    += (a.x + a.y) + (a.z + a.w);
            I    += (v.x + v.y) + (v.z + v.w);
            osum += (c.x + c.y) + (c.z + c.w);
            tsum += (d.x + d.y) + (d.z + d.w);
        }
        float mx = -INFINITY;
#pragma unroll
        for (int c = 0; c < C_; ++c) mx = fmaxf(mx, s_logit[c]);
        float sum = 0.f;
#pragma unroll
        for (int c = 0; c < C_; ++c) sum += __expf(s_logit[c] - mx);
        const int lab = labels[(size_t)b * T_ + t];
        const float p = __expf(s_logit[lab] - mx) / sum;

        const float denom = osum + tsum;
        const float dice = 1.f - (2.f * I + 1.f) / (denom + 1.f);

        out[(size_t)bq * T_ + t] = L - p + dice;
    }
}

extern "C" void kernel_launch(void* const* d_in, const int* in_sizes, int n_in,
                              void* d_out, int out_size, void* d_ws, size_t ws_size,
                              hipStream_t stream) {
    const float* out_probs     = (const float*)d_in[0]; // [B,Q,C]
    const float* out_masks     = (const float*)d_in[1]; // [B,Q,H,W]
    const float* target_masks  = (const float*)d_in[2]; // [B,T,H,W]
    const int*   target_labels = (const int*)d_in[3];   // [B,T]
    float* out = (float*)d_out;                         // [B,Q,T]

    _Float16* g16 = (_Float16*)d_ws;                    // 2.6 MB fp16 g area
    float* fws    = (float*)d_ws;                       // float view (WL_F/WI_F/OS_F/GS_F)

    gconv_kernel<<<B_ * T_ * 4, 256, 0, stream>>>(target_masks, g16);
    partial_kernel<<<B_ * QP_ * S_, 256, 0, stream>>>(out_masks, g16, fws);
    finalize_kernel<<<B_ * Q_, 64, 0, stream>>>(out_probs, target_labels, fws, out);
}

// Round 21
// 34.720 us; speedup vs baseline: 1.2057x; 1.0819x over previous
//
#include <hip/hip_runtime.h>
#include <hip/hip_bf16.h>
#include <math.h>

// Problem constants: B=4, Q=100, T=20, H=W=128 (HW=16384), C=80
#define B_ 4
#define Q_ 100
#define T_ 20
#define C_ 80
#define HW_ 16384
#define HW4_ (HW_ / 4)

#define S_ 8                     // segments over HW
#define QP_ (Q_ / 2)             // 50 query-pairs
#define SEG4_ (HW_ / S_ / 4)     // 512 float4 per segment
#define NIT_ (SEG4_ / 64)        // 8 iterations per wave
#define TW_ 5                    // t's per wave (4 waves = 4 t-strips)

// Workspace float offsets (sub-partial layout: [..][S_][4])
#define WL_OFF 0                                   // [B*Q][T][S_][4] = 256000
#define WI_OFF (B_ * Q_ * T_ * S_ * 4)             // 256000
#define OS_OFF (2 * B_ * Q_ * T_ * S_ * 4)         // 512000: [B*Q][S_][4]
#define GS_OFF (OS_OFF + B_ * Q_ * S_ * 4)         // [B*T][S_][4]

typedef float f32x4 __attribute__((ext_vector_type(4)));

// 4-stage reduce: lanes 0..3 hold disjoint 16-lane partials (sum = wave sum).
__device__ __forceinline__ float wred4(float v) {
    v += __shfl_down(v, 32);
    v += __shfl_down(v, 16);
    v += __shfl_down(v, 8);
    v += __shfl_down(v, 4);
    return v;
}

// One independent wave per (b, qpair, tstrip, seg). No LDS, no barriers.
// Explicit 2-deep register double-buffer: issue iter i+1's 7 loads before
// computing iter i, so the vmcnt wait overlaps ~250 cyc of VALU.
template <bool WITH_G>
__device__ __forceinline__ void partial_body(const f32x4* __restrict__ o4,  // +seg+lane
                                             const f32x4* __restrict__ g4,  // +seg+lane
                                             float* __restrict__ ws,
                                             int blin, int b, int seg,
                                             int lane, int ts) {
    const int t0 = ts * TW_;

    float accL[2][TW_], accI[2][TW_], os[2], gs[TW_];
#pragma unroll
    for (int qi = 0; qi < 2; ++qi) {
        os[qi] = 0.f;
#pragma unroll
        for (int tj = 0; tj < TW_; ++tj) { accL[qi][tj] = 0.f; accI[qi][tj] = 0.f; }
    }
#pragma unroll
    for (int tj = 0; tj < TW_; ++tj) gs[tj] = 0.f;

    f32x4 oc[2], gc[TW_], on[2], gn[TW_];
    // Preload iteration 0.
#pragma unroll
    for (int qi = 0; qi < 2; ++qi) oc[qi] = o4[(size_t)qi * HW4_];
#pragma unroll
    for (int tj = 0; tj < TW_; ++tj) gc[tj] = g4[(size_t)(t0 + tj) * HW4_];

#pragma unroll
    for (int it = 0; it < NIT_; ++it) {
        if (it + 1 < NIT_) {
            const int ofs = (it + 1) * 64;
#pragma unroll
            for (int qi = 0; qi < 2; ++qi) on[qi] = o4[(size_t)qi * HW4_ + ofs];
#pragma unroll
            for (int tj = 0; tj < TW_; ++tj) gn[tj] = g4[(size_t)(t0 + tj) * HW4_ + ofs];
        }
        if (ts == 0) {   // wave-uniform: osum computed by one t-strip only
#pragma unroll
            for (int qi = 0; qi < 2; ++qi)
                os[qi] += (oc[qi].x + oc[qi].y) + (oc[qi].z + oc[qi].w);
        }
        if (WITH_G) {
#pragma unroll
            for (int tj = 0; tj < TW_; ++tj)
                gs[tj] += (gc[tj].x + gc[tj].y) + (gc[tj].z + gc[tj].w);
        }
#pragma unroll
        for (int tj = 0; tj < TW_; ++tj) {
            const f32x4 g = gc[tj];
#pragma unroll
            for (int qi = 0; qi < 2; ++qi) {
                const f32x4 o = oc[qi];
                accL[qi][tj] += (fabsf(o.x - g.x) + fabsf(o.y - g.y)) +
                                (fabsf(o.z - g.z) + fabsf(o.w - g.w));
                accI[qi][tj] = fmaf(o.x, g.x, accI[qi][tj]);
                accI[qi][tj] = fmaf(o.y, g.y, accI[qi][tj]);
                accI[qi][tj] = fmaf(o.z, g.z, accI[qi][tj]);
                accI[qi][tj] = fmaf(o.w, g.w, accI[qi][tj]);
            }
        }
        if (it + 1 < NIT_) {
#pragma unroll
            for (int qi = 0; qi < 2; ++qi) oc[qi] = on[qi];
#pragma unroll
            for (int tj = 0; tj < TW_; ++tj) gc[tj] = gn[tj];
        }
    }

    // Epilogue: 4-stage reduces; lanes 0..3 write sub-partials.
    float* WL = ws + WL_OFF;
    float* WI = ws + WI_OFF;
    float* OS = ws + OS_OFF;
    float* GS = ws + GS_OFF;
#pragma unroll
    for (int qi = 0; qi < 2; ++qi) {
#pragma unroll
        for (int tj = 0; tj < TW_; ++tj) {
            const float vL = wred4(accL[qi][tj]);
            const float vI = wred4(accI[qi][tj]);
            if (lane < 4) {
                const size_t idx = ((size_t)(blin / S_ * 2 + qi) * T_ + t0 + tj) * (S_ * 4)
                                   + seg * 4 + lane;
                WL[idx] = vL;
                WI[idx] = vI;
            }
        }
        if (ts == 0) {
            const float vo = wred4(os[qi]);
            if (lane < 4) OS[(size_t)(blin / S_ * 2 + qi) * (S_ * 4) + seg * 4 + lane] = vo;
        }
    }
    if (WITH_G) {
#pragma unroll
        for (int tj = 0; tj < TW_; ++tj) {
            const float vg = wred4(gs[tj]);
            if (lane < 4) GS[(size_t)(b * T_ + t0 + tj) * (S_ * 4) + seg * 4 + lane] = vg;
        }
    }
}

__global__ __launch_bounds__(256) void partial_kernel(const float* __restrict__ outm,
                                                      const float* __restrict__ tgtm,
                                                      float* __restrict__ ws) {
    // XCD-batch partition: batch b on XCD pair {2b,2b+1}.
    const int r = blockIdx.x & 7;
    const int m = blockIdx.x >> 3;
    const int b = r >> 1;
    const int l = m * 2 + (r & 1);   // [0,400): qp(50) x seg(8)
    const int qp = l >> 3;
    const int seg = l & (S_ - 1);
    const int blin = (b * QP_ + qp) * S_ + seg;   // (blin/S_)*2 == global qpair base

    const int lane = threadIdx.x & 63;
    const int ts   = threadIdx.x >> 6;   // t-strip = wave id

    const f32x4* o4 = (const f32x4*)(outm + ((size_t)b * Q_ + qp * 2) * HW_) + seg * SEG4_ + lane;
    const f32x4* g4 = (const f32x4*)(tgtm + (size_t)b * T_ * HW_) + seg * SEG4_ + lane;

    if (qp == 0) partial_body<true>(o4, g4, ws, blin, b, seg, lane, ts);
    else         partial_body<false>(o4, g4, ws, blin, b, seg, lane, ts);
}

// Kernel 2: reduce seg/sub-partials + epilogue (softmax class cost + dice).
__global__ __launch_bounds__(64) void finalize_kernel(const float* __restrict__ probs,
                                                      const int*   __restrict__ labels,
                                                      const float* __restrict__ ws,
                                                      float* __restrict__ out) {
    const int bq = blockIdx.x;
    const int b = bq / Q_;

    __shared__ float s_logit[C_];
    for (int c = threadIdx.x; c < C_; c += 64)
        s_logit[c] = probs[(size_t)bq * C_ + c];
    __syncthreads();

    const int t = threadIdx.x;
    if (t < T_) {
        const float4* WL4 = (const float4*)(ws + WL_OFF) + ((size_t)bq * T_ + t) * S_;
        const float4* WI4 = (const float4*)(ws + WI_OFF) + ((size_t)bq * T_ + t) * S_;
        const float4* OS4 = (const float4*)(ws + OS_OFF) + (size_t)bq * S_;
        const float4* GS4 = (const float4*)(ws + GS_OFF) + ((size_t)b * T_ + t) * S_;
        float L = 0.f, I = 0.f, osum = 0.f, tsum = 0.f;
#pragma unroll
        for (int s = 0; s < S_; ++s) {
            const float4 a = WL4[s];
            const float4 v = WI4[s];
            const float4 c = OS4[s];
            const float4 d = GS4[s];
            L    += (a.x + a.y) + (a.z + a.w);
            I    += (v.x + v.y) + (v.z + v.w);
            osum += (c.x + c.y) + (c.z + c.w);
            tsum += (d.x + d.y) + (d.z + d.w);
        }
        float mx = -INFINITY;
#pragma unroll
        for (int c = 0; c < C_; ++c) mx = fmaxf(mx, s_logit[c]);
        float sum = 0.f;
#pragma unroll
        for (int c = 0; c < C_; ++c) sum += __expf(s_logit[c] - mx);
        const int lab = labels[(size_t)b * T_ + t];
        const float p = __expf(s_logit[lab] - mx) / sum;

        const float denom = osum + tsum;
        const float dice = 1.f - (2.f * I + 1.f) / (denom + 1.f);

        out[(size_t)bq * T_ + t] = L - p + dice;
    }
}

extern "C" void kernel_launch(void* const* d_in, const int* in_sizes, int n_in,
                              void* d_out, int out_size, void* d_ws, size_t ws_size,
                              hipStream_t stream) {
    const float* out_probs     = (const float*)d_in[0]; // [B,Q,C]
    const float* out_masks     = (const float*)d_in[1]; // [B,Q,H,W]
    const float* target_masks  = (const float*)d_in[2]; // [B,T,H,W]
    const int*   target_labels = (const int*)d_in[3];   // [B,T]
    float* out = (float*)d_out;                         // [B,Q,T]

    float* partials = (float*)d_ws;                     // ~2.1 MB

    partial_kernel<<<B_ * QP_ * S_, 256, 0, stream>>>(out_masks, target_masks, partials);
    finalize_kernel<<<B_ * Q_, 64, 0, stream>>>(out_probs, target_labels, partials, out);
}